// Round 5
// baseline (106.187 us; speedup 1.0000x reference)
//
#include <hip/hip_runtime.h>
#include <hip/hip_bf16.h>

#define C_IN    64
#define C_OUT   128
#define HH      112
#define WW      112
#define NB      16
#define KTOT    576      // C_IN * 9
#define NSTEPS  36       // KTOT / 16
#define PH      114      // padded spatial dim
#define PPIX    (PH*PH)  // 12996
#define NPIX    (HH*WW)  // 12544
#define CHUNK   128      // output pixels per block (4 N-tiles of 32, linear)
#define NCHUNK  (NPIX/CHUNK)   // 98
#define SROWS   4        // staged input rows (r0-1 .. r0+2)
#define SPX     (SROWS*PH)     // 456 staged pixels
#define SCHUNKS (SPX*8)        // 3648 16B-chunks
#define SROUNDS 15             // ceil(3648/256)
#define XT_OFF  147456   // bytes: pw occupies [0, 147456)
#define XT_BYTES ((size_t)NB * PPIX * C_IN * 2)
// fallback tiling (round-2 kernel)
#define TY      8
#define TX      16
#define HALO_X  18
#define HALO_P  180
#define TILES_X 7
#define NTILES  98

typedef __bf16 bf16x8 __attribute__((ext_vector_type(8)));
typedef float  f32x16 __attribute__((ext_vector_type(16)));

static __device__ __forceinline__ unsigned short f2bf(float v) {
    unsigned int u = __builtin_bit_cast(unsigned int, v);
    u = u + 0x7fffu + ((u >> 16) & 1u);   // RNE
    return (unsigned short)(u >> 16);
}

// ---------------- pack spW = weight*mask into bf16 MFMA A-fragments ----------------
// pw_frag[t][mt][lane] = 16 B (8 bf16); k_log(t,g,e)=t*16+g*8+e; ij=k_log>>6, c=k_log&63; k_orig=c*9+ij
__global__ __launch_bounds__(256) void pack_w_kernel(
        const float* __restrict__ weight, const float* __restrict__ mask,
        unsigned short* __restrict__ pw) {
    int t  = blockIdx.x;           // 0..35
    int mt = threadIdx.x >> 6;     // 0..3
    int l  = threadIdx.x & 63;
    int g  = l >> 5;
    int m  = mt * 32 + (l & 31);
    unsigned int words[4];
    #pragma unroll
    for (int ew = 0; ew < 4; ++ew) {
        unsigned int w2[2];
        #pragma unroll
        for (int h = 0; h < 2; ++h) {
            int e    = ew * 2 + h;
            int klog = t * 16 + g * 8 + e;
            int ij   = klog >> 6;
            int c    = klog & 63;
            int ko   = c * 9 + ij;
            w2[h] = f2bf(weight[m * KTOT + ko] * mask[m * KTOT + ko]);
        }
        words[ew] = w2[0] | (w2[1] << 16);
    }
    uint4 o4; o4.x = words[0]; o4.y = words[1]; o4.z = words[2]; o4.w = words[3];
    ((uint4*)pw)[(t * 4 + mt) * 64 + l] = o4;
}

// ---------------- pre-pass: x [b][c][h][w] fp32 -> xT [b][hp][wp][c] bf16, zero-padded ----------------
__global__ __launch_bounds__(256) void transpose_x_kernel(
        const float* __restrict__ x, unsigned short* __restrict__ xT) {
    const int b  = blockIdx.y;
    const int pp = blockIdx.x * 256 + threadIdx.x;
    if (pp >= PPIX) return;
    const int hp = pp / PH, wp = pp - hp * PH;
    const int gh = hp - 1, gw = wp - 1;
    const bool valid = (unsigned)gh < (unsigned)HH && (unsigned)gw < (unsigned)WW;
    const float* src = x + (size_t)b * C_IN * (HH * WW) + (gh * WW + gw);
    uint4* dst = (uint4*)(xT + ((size_t)b * PPIX + pp) * C_IN);
    #pragma unroll
    for (int cb = 0; cb < 8; ++cb) {
        unsigned int w4[4];
        #pragma unroll
        for (int h = 0; h < 4; ++h) {
            float v0 = valid ? src[(size_t)(cb * 8 + h * 2    ) * (HH * WW)] : 0.0f;
            float v1 = valid ? src[(size_t)(cb * 8 + h * 2 + 1) * (HH * WW)] : 0.0f;
            w4[h] = (unsigned)f2bf(v0) | ((unsigned)f2bf(v1) << 16);
        }
        uint4 o; o.x = w4[0]; o.y = w4[1]; o.z = w4[2]; o.w = w4[3];
        dst[cb] = o;
    }
}

// ---------------- main conv: linear-pixel chunks, full-line stores ----------------
// Block = 128 consecutive output pixels (all 128 c_out). Staged LDS = 4 full input
// rows (r0-1..r0+2) x 114 cols, channel-major bf16, slot-swizzled: slot'=(slot^P)&7.
__global__ __launch_bounds__(256, 4) void sparse_conv_xt_kernel(
        const unsigned short* __restrict__ xT, const unsigned short* __restrict__ pw,
        const float* __restrict__ bias, float* __restrict__ out) {
    __shared__ __align__(16) unsigned short xs[SROUNDS * 2048];   // 61440 B (58368 used + tail slack)

    // XCD-bijective swizzle: 1568 % 8 == 0
    const int bid = (blockIdx.x & 7) * (NB * NCHUNK / 8) + (blockIdx.x >> 3);
    const int b   = bid / NCHUNK;
    const int ck  = bid % NCHUNK;
    const int p0  = ck * CHUNK;
    const int r0  = p0 / WW;            // first output row
    const int tid = threadIdx.x;
    const int wave = tid >> 6, l = tid & 63;
    const int wm = wave >> 1, wn = wave & 1;
    const int g  = l >> 5,  ln = l & 31;

    // ---- stage 4 rows x 114 px: 15 rounds of global_load_lds, linear dest, swizzled source ----
    {
        const char* xTb = (const char*)xT + (size_t)b * PPIX * (C_IN * 2);
        const int rowbase = r0 * PH;    // xT pixel index of staged row_local 0 (= input row r0-1)
        #pragma unroll
        for (int r = 0; r < SROUNDS; ++r) {
            int chunk = r * 256 + tid;
            if (chunk > SCHUNKS - 1) chunk = SCHUNKS - 1;   // tail clamp (dup source, dest stays linear)
            int P = chunk >> 3;         // staged pixel 0..455
            int s = chunk & 7;
            const char* gp = xTb + (size_t)(rowbase + P) * (C_IN * 2) + (((s ^ P) & 7) << 4);
            char* lp = (char*)xs + r * 4096 + wave * 1024;  // + lane*16 done by HW
            __builtin_amdgcn_global_load_lds(
                (const __attribute__((address_space(1))) void*)gp,
                (__attribute__((address_space(3))) void*)lp, 16, 0, 0);
        }
    }
    __syncthreads();

    // per-lane tap-base: output pixel p -> (h,w); P00 = (h-r0)*114 + w
    int P00[2];
    #pragma unroll
    for (int ntp = 0; ntp < 2; ++ntp) {
        int p = p0 + (wn * 2 + ntp) * 32 + ln;
        int h = p / WW, w = p - h * WW;
        P00[ntp] = (h - r0) * PH + w;
    }

    f32x16 acc[2][2];
    #pragma unroll
    for (int i = 0; i < 2; ++i)
        #pragma unroll
        for (int jq = 0; jq < 2; ++jq)
            #pragma unroll
            for (int q = 0; q < 16; ++q) acc[i][jq][q] = 0.0f;

    const uint4* __restrict__ pwv = (const uint4*)pw;

    #pragma unroll 1
    for (int ij = 0; ij < 9; ++ij) {
        const int di = ij / 3;
        const int dj = ij - di * 3;
        const int Pa0 = P00[0] + di * PH + dj;
        const int Pa1 = P00[1] + di * PH + dj;
        #pragma unroll
        for (int cs = 0; cs < 4; ++cs) {
            const int t = ij * 4 + cs;
            bf16x8 a0 = __builtin_bit_cast(bf16x8, pwv[(t * 4 + wm * 2 + 0) * 64 + l]);
            bf16x8 a1 = __builtin_bit_cast(bf16x8, pwv[(t * 4 + wm * 2 + 1) * 64 + l]);
            const int jb = cs * 2 + g;   // 16B channel-block index
            bf16x8 b0 = __builtin_bit_cast(bf16x8,
                *(const uint4*)((const char*)xs + Pa0 * (C_IN * 2) + (((jb ^ Pa0) & 7) << 4)));
            bf16x8 b1 = __builtin_bit_cast(bf16x8,
                *(const uint4*)((const char*)xs + Pa1 * (C_IN * 2) + (((jb ^ Pa1) & 7) << 4)));
            acc[0][0] = __builtin_amdgcn_mfma_f32_32x32x16_bf16(a0, b0, acc[0][0], 0, 0, 0);
            acc[0][1] = __builtin_amdgcn_mfma_f32_32x32x16_bf16(a0, b1, acc[0][1], 0, 0, 0);
            acc[1][0] = __builtin_amdgcn_mfma_f32_32x32x16_bf16(a1, b0, acc[1][0], 0, 0, 0);
            acc[1][1] = __builtin_amdgcn_mfma_f32_32x32x16_bf16(a1, b1, acc[1][1], 0, 0, 0);
        }
    }

    // ---- epilogue: full 128B-line stores. C/D: col=lane&31 (pixel), row=(r&3)+8*(r>>2)+4*g ----
    const size_t outb = (size_t)b * C_OUT * NPIX;
    #pragma unroll
    for (int mtp = 0; mtp < 2; ++mtp) {
        #pragma unroll
        for (int r = 0; r < 16; ++r) {
            int mloc = (r & 3) + 8 * (r >> 2) + 4 * g;
            int o = (wm * 2 + mtp) * 32 + mloc;
            float bv = bias[o];
            #pragma unroll
            for (int ntp = 0; ntp < 2; ++ntp) {
                int p = p0 + (wn * 2 + ntp) * 32 + ln;
                out[outb + (size_t)o * NPIX + p] = acc[mtp][ntp][r] + bv;
            }
        }
    }
}

// ---------------- fallback (round-2 kernel) if ws too small for xT ----------------
__global__ __launch_bounds__(256, 4) void sparse_conv_fb_kernel(
        const float* __restrict__ x, const unsigned short* __restrict__ pw,
        const float* __restrict__ bias, float* __restrict__ out) {
    __shared__ __align__(16) unsigned short xs[HALO_P * C_IN];

    const int bid = blockIdx.x;
    const int b   = bid / NTILES;
    const int t98 = bid % NTILES;
    const int tyi = t98 / TILES_X;
    const int txi = t98 % TILES_X;
    const int h0  = tyi * TY, w0 = txi * TX;
    const int tid = threadIdx.x;

    const float* xb = x + (size_t)b * C_IN * HH * WW;
    {
        const int p  = tid;
        const bool act = p < HALO_P;
        int yy = p / HALO_X;
        int xx = p - yy * HALO_X;
        int gh = h0 + yy - 1, gw = w0 + xx - 1;
        const bool valid = act && (unsigned)gh < (unsigned)HH && (unsigned)gw < (unsigned)WW;
        const float* bp = xb + (gh * WW + gw);
        float v[C_IN];
        #pragma unroll
        for (int c = 0; c < C_IN; ++c)
            v[c] = valid ? bp[c * (HH * WW)] : 0.0f;
        if (act) {
            char* xc = (char*)xs + p * (C_IN * 2);
            #pragma unroll
            for (int j = 0; j < 8; ++j) {
                bf16x8 bv;
                #pragma unroll
                for (int e = 0; e < 8; ++e) bv[e] = (__bf16)v[j * 8 + e];
                *(uint4*)(xc + (((j ^ p) & 7) << 4)) = __builtin_bit_cast(uint4, bv);
            }
        }
    }
    __syncthreads();

    const int wave = tid >> 6, l = tid & 63;
    const int wm = wave >> 1, wn = wave & 1;
    const int g  = l >> 5,  ln = l & 31;

    int P0[2];
    #pragma unroll
    for (int ntp = 0; ntp < 2; ++ntp) {
        int pt = wn * 64 + ntp * 32 + ln;
        P0[ntp] = (pt >> 4) * HALO_X + (pt & 15);
    }

    f32x16 acc[2][2];
    #pragma unroll
    for (int i = 0; i < 2; ++i)
        #pragma unroll
        for (int jq = 0; jq < 2; ++jq)
            #pragma unroll
            for (int q = 0; q < 16; ++q) acc[i][jq][q] = 0.0f;

    const uint4* __restrict__ pwv = (const uint4*)pw;

    #pragma unroll 1
    for (int ij = 0; ij < 9; ++ij) {
        const int di = ij / 3;
        const int dj = ij - di * 3;
        const int P0a = P0[0] + di * HALO_X + dj;
        const int P1a = P0[1] + di * HALO_X + dj;
        #pragma unroll
        for (int cs = 0; cs < 4; ++cs) {
            const int t = ij * 4 + cs;
            bf16x8 a0 = __builtin_bit_cast(bf16x8, pwv[(t * 4 + wm * 2 + 0) * 64 + l]);
            bf16x8 a1 = __builtin_bit_cast(bf16x8, pwv[(t * 4 + wm * 2 + 1) * 64 + l]);
            const int jb = cs * 2 + g;
            bf16x8 b0 = __builtin_bit_cast(bf16x8,
                *(const uint4*)((const char*)xs + P0a * (C_IN * 2) + (((jb ^ P0a) & 7) << 4)));
            bf16x8 b1 = __builtin_bit_cast(bf16x8,
                *(const uint4*)((const char*)xs + P1a * (C_IN * 2) + (((jb ^ P1a) & 7) << 4)));
            acc[0][0] = __builtin_amdgcn_mfma_f32_32x32x16_bf16(a0, b0, acc[0][0], 0, 0, 0);
            acc[0][1] = __builtin_amdgcn_mfma_f32_32x32x16_bf16(a0, b1, acc[0][1], 0, 0, 0);
            acc[1][0] = __builtin_amdgcn_mfma_f32_32x32x16_bf16(a1, b0, acc[1][0], 0, 0, 0);
            acc[1][1] = __builtin_amdgcn_mfma_f32_32x32x16_bf16(a1, b1, acc[1][1], 0, 0, 0);
        }
    }

    const size_t outb = (size_t)b * C_OUT * HH * WW;
    #pragma unroll
    for (int mtp = 0; mtp < 2; ++mtp) {
        #pragma unroll
        for (int r = 0; r < 16; ++r) {
            int mloc = (r & 3) + 8 * (r >> 2) + 4 * g;
            int o = (wm * 2 + mtp) * 32 + mloc;
            float bv = bias[o];
            #pragma unroll
            for (int ntp = 0; ntp < 2; ++ntp) {
                int p  = wn * 64 + ntp * 32 + ln;
                int gh = h0 + (p >> 4), gw = w0 + (p & 15);
                out[outb + ((size_t)o * HH + gh) * WW + gw] = acc[mtp][ntp][r] + bv;
            }
        }
    }
}

extern "C" void kernel_launch(void* const* d_in, const int* in_sizes, int n_in,
                              void* d_out, int out_size, void* d_ws, size_t ws_size,
                              hipStream_t stream) {
    const float* x    = (const float*)d_in[0];
    const float* w    = (const float*)d_in[1];
    const float* mk   = (const float*)d_in[2];
    const float* bs   = (const float*)d_in[3];
    float* out        = (float*)d_out;
    unsigned short* pw = (unsigned short*)d_ws;   // [0, 147456)

    pack_w_kernel<<<dim3(NSTEPS), dim3(256), 0, stream>>>(w, mk, pw);

    if (ws_size >= (size_t)XT_OFF + XT_BYTES) {
        unsigned short* xT = (unsigned short*)((char*)d_ws + XT_OFF);
        transpose_x_kernel<<<dim3((PPIX + 255) / 256, NB), dim3(256), 0, stream>>>(x, xT);
        sparse_conv_xt_kernel<<<dim3(NB * NCHUNK), dim3(256), 0, stream>>>(xT, pw, bs, out);
    } else {
        sparse_conv_fb_kernel<<<dim3(NB * NTILES), dim3(256), 0, stream>>>(x, pw, bs, out);
    }
}

// Round 6
// 76.483 us; speedup vs baseline: 1.3884x; 1.3884x over previous
//
#include <hip/hip_runtime.h>
#include <hip/hip_bf16.h>

#define C_IN    64
#define C_OUT   128
#define HH      112
#define WW      112
#define NB      16
#define KTOT    576      // C_IN * 9
#define NSTEPS  36       // KTOT / 16
#define NPIX    (HH*WW)  // 12544
#define PH      114      // padded spatial dim
#define PPIX    (PH*PH)  // 12996
#define XT_OFF  147456   // bytes: pw occupies [0, 147456)
#define XT_BYTES ((size_t)NB * PPIX * C_IN * 2)
// mega-block tiling
#define TILE_H  16
#define TILE_W  16
#define HB_X    18
#define HB_P    324      // 18*18 halo pixels
#define A_BYTES 73728    // 36 t * 2 mt * 64 lanes * 16 B
#define B_BYTES 49152    // 6 staging rounds * 8192 (41472 used)
// fallback tiling (round-2 kernel)
#define TY      8
#define TX      16
#define HALO_X  18
#define HALO_P  180
#define TILES_X 7
#define NTILES  98

typedef __bf16 bf16x8 __attribute__((ext_vector_type(8)));
typedef float  f32x16 __attribute__((ext_vector_type(16)));

static __device__ __forceinline__ unsigned short f2bf(float v) {
    unsigned int u = __builtin_bit_cast(unsigned int, v);
    u = u + 0x7fffu + ((u >> 16) & 1u);   // RNE
    return (unsigned short)(u >> 16);
}

// ---------------- pack spW = weight*mask into bf16 MFMA A-fragments ----------------
// pw_frag[t][mt][lane] = 16 B (8 bf16); k_log(t,g,e)=t*16+g*8+e; ij=k_log>>6, c=k_log&63; k_orig=c*9+ij
__global__ __launch_bounds__(256) void pack_w_kernel(
        const float* __restrict__ weight, const float* __restrict__ mask,
        unsigned short* __restrict__ pw) {
    int t  = blockIdx.x;           // 0..35
    int mt = threadIdx.x >> 6;     // 0..3
    int l  = threadIdx.x & 63;
    int g  = l >> 5;
    int m  = mt * 32 + (l & 31);
    unsigned int words[4];
    #pragma unroll
    for (int ew = 0; ew < 4; ++ew) {
        unsigned int w2[2];
        #pragma unroll
        for (int h = 0; h < 2; ++h) {
            int e    = ew * 2 + h;
            int klog = t * 16 + g * 8 + e;
            int ij   = klog >> 6;
            int c    = klog & 63;
            int ko   = c * 9 + ij;
            w2[h] = f2bf(weight[m * KTOT + ko] * mask[m * KTOT + ko]);
        }
        words[ew] = w2[0] | (w2[1] << 16);
    }
    uint4 o4; o4.x = words[0]; o4.y = words[1]; o4.z = words[2]; o4.w = words[3];
    ((uint4*)pw)[(t * 4 + mt) * 64 + l] = o4;
}

// ---------------- pre-pass: x [b][c][h][w] fp32 -> xT [b][hp][wp][c] bf16, zero-padded ----------------
__global__ __launch_bounds__(256) void transpose_x_kernel(
        const float* __restrict__ x, unsigned short* __restrict__ xT) {
    const int b  = blockIdx.y;
    const int pp = blockIdx.x * 256 + threadIdx.x;
    if (pp >= PPIX) return;
    const int hp = pp / PH, wp = pp - hp * PH;
    const int gh = hp - 1, gw = wp - 1;
    const bool valid = (unsigned)gh < (unsigned)HH && (unsigned)gw < (unsigned)WW;
    const float* src = x + (size_t)b * C_IN * (HH * WW) + (gh * WW + gw);
    uint4* dst = (uint4*)(xT + ((size_t)b * PPIX + pp) * C_IN);
    #pragma unroll
    for (int cb = 0; cb < 8; ++cb) {
        unsigned int w4[4];
        #pragma unroll
        for (int h = 0; h < 4; ++h) {
            float v0 = valid ? src[(size_t)(cb * 8 + h * 2    ) * (HH * WW)] : 0.0f;
            float v1 = valid ? src[(size_t)(cb * 8 + h * 2 + 1) * (HH * WW)] : 0.0f;
            w4[h] = (unsigned)f2bf(v0) | ((unsigned)f2bf(v1) << 16);
        }
        uint4 o; o.x = w4[0]; o.y = w4[1]; o.z = w4[2]; o.w = w4[3];
        dst[cb] = o;
    }
}

// ---------------- main conv: A-resident mega-block ----------------
// Block (512 thr, 8 waves) owns M-half mh (64 c_out) of one column strip (16-px wide)
// of one image. A (36 t x 2 mt x 64 lanes x 16B = 73.7 KB) staged in LDS ONCE, then
// 7 iterations over 16x16-px tiles: stage 18x18 halo (41.5 KB) -> 36 MFMA steps.
// Wave w = N-tile w (32 px); every wave computes both M-tiles of the half.
__global__ __launch_bounds__(512, 2) void sparse_conv_mega_kernel(
        const unsigned short* __restrict__ xT, const unsigned short* __restrict__ pw,
        const float* __restrict__ bias, float* __restrict__ out) {
    __shared__ __align__(16) unsigned char smem[A_BYTES + B_BYTES];   // 122880 B
    unsigned char* As = smem;
    unsigned char* Bs = smem + A_BYTES;

    // XCD-bijective swizzle: 224 % 8 == 0
    const int bid = (blockIdx.x & 7) * 28 + (blockIdx.x >> 3);
    const int b   = bid / 14;
    const int rem = bid % 14;
    const int mh  = rem & 1;        // M-half; mh pairs adjacent -> same xT reads on same XCD
    const int wx  = rem >> 1;       // 0..6 column strip
    const int w0  = wx * TILE_W;
    const int tid = threadIdx.x;
    const int wave = tid >> 6, l = tid & 63;
    const int g = l >> 5, ln = l & 31;

    const char* xTb = (const char*)xT + (size_t)b * PPIX * (C_IN * 2);

    // ---- stage A once: 9 rounds of global_load_lds (exactly 73728 B, linear) ----
    {
        const char* pwb = (const char*)pw;
        #pragma unroll
        for (int r = 0; r < 9; ++r) {
            int c  = r * 512 + tid;          // c = (t*2+mt)*64 + lane
            int t  = c >> 7;
            int mt = (c >> 6) & 1;
            int ll = c & 63;
            const char* gp = pwb + (size_t)((t * 4 + mh * 2 + mt) * 64 + ll) * 16;
            char* lp = (char*)As + r * 8192 + wave * 1024;   // + lane*16 by HW
            __builtin_amdgcn_global_load_lds(
                (const __attribute__((address_space(1))) void*)gp,
                (__attribute__((address_space(3))) void*)lp, 16, 0, 0);
        }
    }

    // per-lane output pixel within tile
    const int pl = wave * 32 + ln;      // 0..255
    const int py = pl >> 4, px = pl & 15;

    // hoist bias into regs (acc init), o = mh*64 + mtp*32 + mloc
    float bv[2][16];
    #pragma unroll
    for (int mtp = 0; mtp < 2; ++mtp)
        #pragma unroll
        for (int r = 0; r < 16; ++r) {
            int mloc = (r & 3) + 8 * (r >> 2) + 4 * g;
            bv[mtp][r] = bias[mh * 64 + mtp * 32 + mloc];
        }

    const size_t outb = (size_t)b * C_OUT * NPIX;

    #pragma unroll 1
    for (int it = 0; it < 7; ++it) {
        const int h0 = it * TILE_H;

        // ---- stage B halo 18x18: 6 rounds (2592 chunks used, tail clamped) ----
        #pragma unroll
        for (int r = 0; r < 6; ++r) {
            int chunk = r * 512 + tid;
            if (chunk > HB_P * 8 - 1) chunk = HB_P * 8 - 1;   // dup tail, dest linear
            int p = chunk >> 3, s = chunk & 7;
            int yy = p / HB_X, xx = p - yy * HB_X;
            const char* gp = xTb + (size_t)((h0 + yy) * PH + (w0 + xx)) * (C_IN * 2)
                                 + (((s ^ p) & 7) << 4);
            char* lp = (char*)Bs + r * 8192 + wave * 1024;
            __builtin_amdgcn_global_load_lds(
                (const __attribute__((address_space(1))) void*)gp,
                (__attribute__((address_space(3))) void*)lp, 16, 0, 0);
        }
        __syncthreads();   // drain staging (A too on it=0)

        f32x16 acc[2];
        #pragma unroll
        for (int mtp = 0; mtp < 2; ++mtp)
            #pragma unroll
            for (int q = 0; q < 16; ++q) acc[mtp][q] = 0.0f;
        // fold bias into acc at r-positions
        #pragma unroll
        for (int mtp = 0; mtp < 2; ++mtp)
            #pragma unroll
            for (int r = 0; r < 16; ++r) acc[mtp][r] = bv[mtp][r];

        #pragma unroll 1
        for (int ij = 0; ij < 9; ++ij) {
            const int di = ij / 3, dj = ij - di * 3;
            const int Pa = (py + di) * HB_X + (px + dj);
            #pragma unroll
            for (int cs = 0; cs < 4; ++cs) {
                const int t = ij * 4 + cs;
                bf16x8 a0 = __builtin_bit_cast(bf16x8,
                    *(const uint4*)(As + ((t * 2 + 0) * 64 + l) * 16));
                bf16x8 a1 = __builtin_bit_cast(bf16x8,
                    *(const uint4*)(As + ((t * 2 + 1) * 64 + l) * 16));
                const int jb = cs * 2 + g;
                bf16x8 bb = __builtin_bit_cast(bf16x8,
                    *(const uint4*)(Bs + Pa * (C_IN * 2) + (((jb ^ Pa) & 7) << 4)));
                acc[0] = __builtin_amdgcn_mfma_f32_32x32x16_bf16(a0, bb, acc[0], 0, 0, 0);
                acc[1] = __builtin_amdgcn_mfma_f32_32x32x16_bf16(a1, bb, acc[1], 0, 0, 0);
            }
        }

        // ---- epilogue: C/D col=lane&31 (pixel), row=(r&3)+8*(r>>2)+4*g ----
        #pragma unroll
        for (int mtp = 0; mtp < 2; ++mtp) {
            #pragma unroll
            for (int r = 0; r < 16; ++r) {
                int mloc = (r & 3) + 8 * (r >> 2) + 4 * g;
                int o = mh * 64 + mtp * 32 + mloc;
                out[outb + (size_t)o * NPIX + (h0 + py) * WW + (w0 + px)] = acc[mtp][r];
            }
        }
        __syncthreads();   // protect Bs from next iter's staging
    }
}

// ---------------- fallback (round-2 kernel) if ws too small for xT ----------------
__global__ __launch_bounds__(256, 4) void sparse_conv_fb_kernel(
        const float* __restrict__ x, const unsigned short* __restrict__ pw,
        const float* __restrict__ bias, float* __restrict__ out) {
    __shared__ __align__(16) unsigned short xs[HALO_P * C_IN];

    const int bid = blockIdx.x;
    const int b   = bid / NTILES;
    const int t98 = bid % NTILES;
    const int tyi = t98 / TILES_X;
    const int txi = t98 % TILES_X;
    const int h0  = tyi * TY, w0 = txi * TX;
    const int tid = threadIdx.x;

    const float* xb = x + (size_t)b * C_IN * HH * WW;
    {
        const int p  = tid;
        const bool act = p < HALO_P;
        int yy = p / HALO_X;
        int xx = p - yy * HALO_X;
        int gh = h0 + yy - 1, gw = w0 + xx - 1;
        const bool valid = act && (unsigned)gh < (unsigned)HH && (unsigned)gw < (unsigned)WW;
        const float* bp = xb + (gh * WW + gw);
        float v[C_IN];
        #pragma unroll
        for (int c = 0; c < C_IN; ++c)
            v[c] = valid ? bp[c * (HH * WW)] : 0.0f;
        if (act) {
            char* xc = (char*)xs + p * (C_IN * 2);
            #pragma unroll
            for (int j = 0; j < 8; ++j) {
                bf16x8 bvv;
                #pragma unroll
                for (int e = 0; e < 8; ++e) bvv[e] = (__bf16)v[j * 8 + e];
                *(uint4*)(xc + (((j ^ p) & 7) << 4)) = __builtin_bit_cast(uint4, bvv);
            }
        }
    }
    __syncthreads();

    const int wave = tid >> 6, l = tid & 63;
    const int wm = wave >> 1, wn = wave & 1;
    const int g  = l >> 5,  ln = l & 31;

    int P0[2];
    #pragma unroll
    for (int ntp = 0; ntp < 2; ++ntp) {
        int pt = wn * 64 + ntp * 32 + ln;
        P0[ntp] = (pt >> 4) * HALO_X + (pt & 15);
    }

    f32x16 acc[2][2];
    #pragma unroll
    for (int i = 0; i < 2; ++i)
        #pragma unroll
        for (int jq = 0; jq < 2; ++jq)
            #pragma unroll
            for (int q = 0; q < 16; ++q) acc[i][jq][q] = 0.0f;

    const uint4* __restrict__ pwv = (const uint4*)pw;

    #pragma unroll 1
    for (int ij = 0; ij < 9; ++ij) {
        const int di = ij / 3;
        const int dj = ij - di * 3;
        const int P0a = P0[0] + di * HALO_X + dj;
        const int P1a = P0[1] + di * HALO_X + dj;
        #pragma unroll
        for (int cs = 0; cs < 4; ++cs) {
            const int t = ij * 4 + cs;
            bf16x8 a0 = __builtin_bit_cast(bf16x8, pwv[(t * 4 + wm * 2 + 0) * 64 + l]);
            bf16x8 a1 = __builtin_bit_cast(bf16x8, pwv[(t * 4 + wm * 2 + 1) * 64 + l]);
            const int jb = cs * 2 + g;
            bf16x8 b0 = __builtin_bit_cast(bf16x8,
                *(const uint4*)((const char*)xs + P0a * (C_IN * 2) + (((jb ^ P0a) & 7) << 4)));
            bf16x8 b1 = __builtin_bit_cast(bf16x8,
                *(const uint4*)((const char*)xs + P1a * (C_IN * 2) + (((jb ^ P1a) & 7) << 4)));
            acc[0][0] = __builtin_amdgcn_mfma_f32_32x32x16_bf16(a0, b0, acc[0][0], 0, 0, 0);
            acc[0][1] = __builtin_amdgcn_mfma_f32_32x32x16_bf16(a0, b1, acc[0][1], 0, 0, 0);
            acc[1][0] = __builtin_amdgcn_mfma_f32_32x32x16_bf16(a1, b0, acc[1][0], 0, 0, 0);
            acc[1][1] = __builtin_amdgcn_mfma_f32_32x32x16_bf16(a1, b1, acc[1][1], 0, 0, 0);
        }
    }

    const size_t outb = (size_t)b * C_OUT * HH * WW;
    #pragma unroll
    for (int mtp = 0; mtp < 2; ++mtp) {
        #pragma unroll
        for (int r = 0; r < 16; ++r) {
            int mloc = (r & 3) + 8 * (r >> 2) + 4 * g;
            int o = (wm * 2 + mtp) * 32 + mloc;
            float bvv = bias[o];
            #pragma unroll
            for (int ntp = 0; ntp < 2; ++ntp) {
                int p  = wn * 64 + ntp * 32 + ln;
                int gh = h0 + (p >> 4), gw = w0 + (p & 15);
                out[outb + ((size_t)o * HH + gh) * WW + gw] = acc[mtp][ntp][r] + bvv;
            }
        }
    }
}

extern "C" void kernel_launch(void* const* d_in, const int* in_sizes, int n_in,
                              void* d_out, int out_size, void* d_ws, size_t ws_size,
                              hipStream_t stream) {
    const float* x    = (const float*)d_in[0];
    const float* w    = (const float*)d_in[1];
    const float* mk   = (const float*)d_in[2];
    const float* bs   = (const float*)d_in[3];
    float* out        = (float*)d_out;
    unsigned short* pw = (unsigned short*)d_ws;   // [0, 147456)

    pack_w_kernel<<<dim3(NSTEPS), dim3(256), 0, stream>>>(w, mk, pw);

    if (ws_size >= (size_t)XT_OFF + XT_BYTES) {
        unsigned short* xT = (unsigned short*)((char*)d_ws + XT_OFF);
        transpose_x_kernel<<<dim3((PPIX + 255) / 256, NB), dim3(256), 0, stream>>>(x, xT);
        sparse_conv_mega_kernel<<<dim3(224), dim3(512), 0, stream>>>(xT, pw, bs, out);
    } else {
        sparse_conv_fb_kernel<<<dim3(NB * NTILES), dim3(256), 0, stream>>>(x, pw, bs, out);
    }
}